// Round 12
// baseline (473.719 us; speedup 1.0000x reference)
//
#include <hip/hip_runtime.h>
#include <stdint.h>

// x: (32, 256, 58, 58) f32 binary {0,1};  w: (256, 256, 3, 3) f32
// out: (32, 256, 56, 56) f32 = alpha[o]*(2S - 2304)
// R15: i8 MFMA implicit conv, WIDE WAVES (2Mx4N per wave).
// R14 post-mortem: waves_per_eu(4) squeezed arch regs to 64 -> scratch
// spills (FETCH +13MB / WRITE +28MB witness) and asm volatile pinned the
// scheduler -> 123us regression. Reverted both.
// R13 model: T ~= 250cyc/step with only 32cyc of MFMA per wave-step and
// ~2.7 waves/SIMD -> 34% duty. Fix: 256-thr blocks, 4 waves, each wave
// 2Mx4N tiles = 8 MFMA (64cyc) per 2 A-ds_reads (pipelined 1 step ahead),
// B 2-deep register prefetch from global (L2-resident). 2 waves/SIMD x
// 64cyc ~= T -> pipe near-saturated.

#define BATCH 32
#define C_IN 256
#define OCH 256
#define HIN 58
#define WIN2 58
#define HOUT 56
#define WOUT 56
#define TAPS 9
#define WWORDS 8            // 256 channels / 32 bits
#define HWIN (HIN * WIN2)   // 3364
#define HWOUT (HOUT * WOUT) // 3136
#define NPOS (BATCH * HWIN) // 107648

#define AP 144              // LDS bytes per input position (128 ch + 16 pad:
                            // 16B-slot stride 9 (odd) -> b128 slots rotate, ~conflict-free)

typedef int   i32x4  __attribute__((ext_vector_type(4)));
typedef int   i32x16 __attribute__((ext_vector_type(16)));
typedef float f32x4  __attribute__((ext_vector_type(4)));

// MFMA inline asm (verified R9/R10/R14, absmax 0.0). "+a": AGPR-native
// accumulator, no copies; NON-volatile so the scheduler may interleave.
#define MFMA(acc, va, vb) \
    asm("v_mfma_i32_32x32x32_i8 %0, %1, %2, %0" : "+a"(acc) : "v"(va), "v"(vb))

// ---------------------------------------------------------------------------
// Kernel 1: bit-pack x. Thread <-> one position, all 8 words (R14, verified).
// Reads 256B-coalesced per channel step; writes 32B/lane contiguous.
// ---------------------------------------------------------------------------
__global__ __launch_bounds__(256) void pack_x_kernel(
    const float* __restrict__ x, uint32_t* __restrict__ xp)
{
    int p = blockIdx.x * 256 + threadIdx.x;      // 421 blocks, tail-guarded
    if (p >= NPOS) return;
    int b = p / HWIN;
    int r = p - b * HWIN;
    const float* xb = x + (size_t)b * C_IN * HWIN + r;
    uint32_t w[8];
    #pragma unroll
    for (int k = 0; k < 8; ++k) {
        uint32_t m = 0u;
        #pragma unroll
        for (int j = 0; j < 32; ++j)
            m |= (xb[(size_t)(k * 32 + j) * HWIN] > 0.5f ? 1u : 0u) << j;
        w[k] = m;
    }
    *(uint4*)(xp + (size_t)p * WWORDS)     = make_uint4(w[0], w[1], w[2], w[3]);
    *(uint4*)(xp + (size_t)p * WWORDS + 4) = make_uint4(w[4], w[5], w[6], w[7]);
}

// ---------------------------------------------------------------------------
// Kernel 2: pack weights to i8 {+1,-1}, STEP-MAJOR (unchanged, verified):
//   wq8s[((s*2 + e)*256 + o)*16 + j], s = kh*36 + tap*4 + kb,
//   weight channel c = kh*128 + kb*32 + e*16 + j. Also alpha per o.
// ---------------------------------------------------------------------------
__global__ __launch_bounds__(256) void pack_w8_kernel(
    const float* __restrict__ wt, char* __restrict__ wq8s, float* __restrict__ sA)
{
    int o = blockIdx.x;
    int c = threadIdx.x;
    const float* wb = wt + ((size_t)o * C_IN + c) * TAPS;
    float s = 0.f;
    char sg[TAPS];
    #pragma unroll
    for (int t = 0; t < TAPS; ++t) {
        float v = wb[t];
        s += fabsf(v);
        sg[t] = (v >= 0.0f) ? (char)1 : (char)-1;
    }
    int kh = c >> 7;
    int kb = (c >> 5) & 3;
    int e  = (c >> 4) & 1;
    int j  = c & 15;
    #pragma unroll
    for (int t = 0; t < TAPS; ++t) {
        int st = kh * 36 + t * 4 + kb;
        wq8s[(size_t)((st * 2 + e) * 256 + o) * 16 + j] = sg[t];
    }

    __shared__ float red[256];
    red[c] = s;
    __syncthreads();
    for (int off = 128; off > 0; off >>= 1) {
        if (c < off) red[c] += red[c + off];
        __syncthreads();
    }
    if (c == 0) sA[o] = red[0] / (float)(C_IN * HWIN);
}

// ---------------------------------------------------------------------------
// Kernel 3: main i8-MFMA conv. Block = 2 output rows (M=128: 112 valid) x
// N=256 o, 256 threads = 4 waves; wave (wv) = mgrp (wv&1, M-half) x
// ngrp (wv>>1, 128-o half) -> 2Mx4N = 8 accumulators of 16 AGPRs.
// A: bit->+-1 expand into LDS per K-half (stride AP=144), restaged once;
//    frag ds_reads pipelined one step ahead (reload across restage).
// B: registers straight from global (L2-resident), 2-deep prefetch.
// ---------------------------------------------------------------------------
__global__ __launch_bounds__(256)
void xnor_mfma_kernel(
    const uint32_t* __restrict__ xp, const char* __restrict__ wq8s,
    const float* __restrict__ sA, float* __restrict__ out)
{
    __shared__ __attribute__((aligned(16))) char lds[36864]; // A 33,408 / Cbuf 36,864
    char* Alds = lds;
    float* Cbuf = (float*)lds;                   // epilogue alias

    int blk = blockIdx.x;                        // 0..895
    int b   = blk / 28;                          // 28 row-pairs per image
    int rp  = blk - b * 28;
    int oy0 = rp * 2;
    int tid  = threadIdx.x;
    int wv   = tid >> 6;                         // 0..3
    int lane = tid & 63;
    int l31  = lane & 31;
    int e    = lane >> 5;
    int mgrp = wv & 1;                           // M-half of this wave
    int ngrp = wv >> 1;                          // 128-o half

    // Per-lane A-frag base for the wave's 2 M-subtiles (row = l31).
    int baseA[2];
    #pragma unroll
    for (int mi = 0; mi < 2; ++mi) {
        int p = (mgrp * 2 + mi) * 32 + l31;      // 0..127
        int r = (p * 586) >> 15;                 // p/56 exact for p<=127
        int c = p - 56 * r;
        baseA[mi] = (r * 58 + c) * AP + e * 16;
    }
    // B-fragment per-lane base in step-major wq8s; step stride = 8192 B;
    // the wave's 4 o-subtiles sit at +0, +512, +1024, +1536.
    const char* pb = wq8s + ((size_t)e * 256 + (size_t)(ngrp * 128 + l31)) * 16;
    float al[4];
    #pragma unroll
    for (int ni = 0; ni < 4; ++ni) al[ni] = sA[ngrp * 128 + ni * 32 + l31];

    i32x16 acc00 = {0}, acc01 = {0}, acc02 = {0}, acc03 = {0};
    i32x16 acc10 = {0}, acc11 = {0}, acc12 = {0}, acc13 = {0};
    asm volatile("s_nop 7\n\ts_nop 7");          // accvgpr_write -> MFMA srcC guard

// A K-step LDS offset (compile-time under full unroll).
#define KA(s) ((((((s) % 36) >> 2) / 3) * 58 + ((((s) % 36) >> 2) % 3)) * AP + ((s) & 3) * 32)

// Expand bit-packed x into +-1 bytes for K-half KH (multiply-spread,
// verified R9-R14). 1856 16B-items by 256 threads, guarded strided loop.
#define STAGE_A(KH)                                                        \
    {                                                                      \
        _Pragma("unroll")                                                  \
        for (int it = 0; it < 8; ++it) {                                   \
            int L = it * 256 + tid;                                        \
            if (L < 1856) {                                                \
                int ir = L / 464;                                          \
                int rem = L - ir * 464;                                    \
                int iw = rem >> 3, c16 = rem & 7;                          \
                uint32_t wvx = xp[((size_t)(b * HIN + oy0 + ir) * WIN2 + iw) * WWORDS \
                                  + (KH) * 4 + (c16 >> 1)];                \
                uint32_t bits = (c16 & 1) ? (wvx >> 16) : (wvx & 0xFFFFu); \
                i32x4 v;                                                   \
                _Pragma("unroll")                                          \
                for (int d = 0; d < 4; ++d) {                              \
                    uint32_t n  = (bits >> (4 * d)) & 0xFu;                \
                    uint32_t sp = (n * 0x204081u) & 0x01010101u;           \
                    v[d] = (int)~(sp * 0xFEu);                             \
                }                                                          \
                *(i32x4*)(Alds + (ir * 58 + iw) * AP + c16 * 16) = v;      \
            }                                                              \
        }                                                                  \
    }

    STAGE_A(0);

    // B prefetch prologue: steps 0,1 in registers (2-deep).
    i32x4 rb0[2], rb1[2], rb2[2], rb3[2];
    #pragma unroll
    for (int q = 0; q < 2; ++q) {
        rb0[q] = *(const i32x4*)(pb + (size_t)q * 8192);
        rb1[q] = *(const i32x4*)(pb + (size_t)q * 8192 + 512);
        rb2[q] = *(const i32x4*)(pb + (size_t)q * 8192 + 1024);
        rb3[q] = *(const i32x4*)(pb + (size_t)q * 8192 + 1536);
    }
    __syncthreads();

    // A pipeline prologue: step 0 fragments.
    i32x4 a0c = *(const i32x4*)(Alds + baseA[0] + KA(0));
    i32x4 a1c = *(const i32x4*)(Alds + baseA[1] + KA(0));

    #pragma unroll
    for (int s = 0; s < 72; ++s) {               // s = kh*36 + tap*4 + kb
        if (s == 36) {                           // half-K A restage
            __syncthreads();
            STAGE_A(1);
            __syncthreads();
            a0c = *(const i32x4*)(Alds + baseA[0] + KA(36));
            a1c = *(const i32x4*)(Alds + baseA[1] + KA(36));
        }
        // B prefetch for s+2 (tail reload harmless).
        const int s2 = (s + 2 > 71) ? 71 : s + 2;
        i32x4 nb0 = *(const i32x4*)(pb + (size_t)s2 * 8192);
        i32x4 nb1 = *(const i32x4*)(pb + (size_t)s2 * 8192 + 512);
        i32x4 nb2 = *(const i32x4*)(pb + (size_t)s2 * 8192 + 1024);
        i32x4 nb3 = *(const i32x4*)(pb + (size_t)s2 * 8192 + 1536);
        // A prefetch for s+1 (same half; boundary steps reload current).
        const int sn = (s == 35 || s == 71) ? s : s + 1;
        i32x4 na0 = *(const i32x4*)(Alds + baseA[0] + KA(sn));
        i32x4 na1 = *(const i32x4*)(Alds + baseA[1] + KA(sn));

        i32x4 b0 = rb0[s & 1];
        i32x4 b1 = rb1[s & 1];
        i32x4 b2 = rb2[s & 1];
        i32x4 b3 = rb3[s & 1];
        MFMA(acc00, a0c, b0);
        MFMA(acc01, a0c, b1);
        MFMA(acc02, a0c, b2);
        MFMA(acc03, a0c, b3);
        MFMA(acc10, a1c, b0);
        MFMA(acc11, a1c, b1);
        MFMA(acc12, a1c, b2);
        MFMA(acc13, a1c, b3);

        rb0[s & 1] = nb0; rb1[s & 1] = nb1; rb2[s & 1] = nb2; rb3[s & 1] = nb3;
        a0c = na0; a1c = na1;
    }

    asm volatile("s_nop 7\n\ts_nop 7");          // MFMA -> accvgpr_read guard

    // Epilogue (layout verified R9-R14): D col = l31,
    // row = (reg&3) + 8*(reg>>2) + 4*e. 4 quarter-M phases via Cbuf[o][36].
    size_t ob = ((size_t)b * OCH) * HWOUT + (size_t)oy0 * WOUT;
    #pragma unroll
    for (int q = 0; q < 4; ++q) {
        __syncthreads();
        if (mgrp == (q >> 1)) {
            const int mi = q & 1;
            #pragma unroll
            for (int ni = 0; ni < 4; ++ni) {
                int o = ngrp * 128 + ni * 32 + l31;
                i32x16 A;
                if (mi == 0) {
                    if      (ni == 0) A = acc00;
                    else if (ni == 1) A = acc01;
                    else if (ni == 2) A = acc02;
                    else              A = acc03;
                } else {
                    if      (ni == 0) A = acc10;
                    else if (ni == 1) A = acc11;
                    else if (ni == 2) A = acc12;
                    else              A = acc13;
                }
                float alv = al[ni];
                #pragma unroll
                for (int g = 0; g < 4; ++g) {
                    f32x4 vv;
                    vv[0] = alv * (float)A[4 * g + 0];
                    vv[1] = alv * (float)A[4 * g + 1];
                    vv[2] = alv * (float)A[4 * g + 2];
                    vv[3] = alv * (float)A[4 * g + 3];
                    int pl = g * 8 + 4 * e;                // pos within quarter
                    *(f32x4*)(Cbuf + (size_t)o * 36 + pl) = vv;
                }
            }
        }
        __syncthreads();
        #pragma unroll 1
        for (int i = 0; i < 32; ++i) {           // flush 256 o x 32 pos
            int idx = i * 256 + tid;
            int o = idx >> 5, pl = idx & 31;
            int pg = q * 32 + pl;
            if (pg < 112) {
                int r = (pg >= 56) ? 1 : 0;
                int c = pg - 56 * r;
                out[ob + (size_t)o * HWOUT + r * WOUT + c] = Cbuf[o * 36 + pl];
            }
        }
    }
#undef STAGE_A
#undef KA
}

// ---------------------------------------------------------------------------
extern "C" void kernel_launch(void* const* d_in, const int* in_sizes, int n_in,
                              void* d_out, int out_size, void* d_ws, size_t ws_size,
                              hipStream_t stream)
{
    const float* x  = (const float*)d_in[0];
    const float* wt = (const float*)d_in[1];
    float* out = (float*)d_out;

    char* ws = (char*)d_ws;
    uint32_t* xp   = (uint32_t*)ws;                         // 3,444,736 B
    char*     wq8s = (char*)(ws + 3444736);                 //   589,824 B
    float*    sAp  = (float*)(ws + 3444736 + 589824);       //     1,024 B

    // 1) pack x bits: 421 blocks (tail-guarded)
    pack_x_kernel<<<dim3((NPOS + 255) / 256), dim3(256), 0, stream>>>(x, xp);

    // 2) pack weights to +-1 i8, step-major + alpha
    pack_w8_kernel<<<dim3(OCH), dim3(256), 0, stream>>>(wt, wq8s, sAp);

    // 3) main: 32 images x 28 output-row-pairs, 256 threads (4 wide waves)
    xnor_mfma_kernel<<<dim3(896), dim3(256), 0, stream>>>(xp, wq8s, sAp, out);
}

// Round 13
// 269.787 us; speedup vs baseline: 1.7559x; 1.7559x over previous
//
#include <hip/hip_runtime.h>
#include <stdint.h>

// x: (32, 256, 58, 58) f32 binary {0,1};  w: (256, 256, 3, 3) f32
// out: (32, 256, 56, 56) f32 = alpha[o]*(2S - 2304)
// R16: R13 skeleton restored (86.2us verified) + two surgical changes:
//  (1) acc constraint "+v" -> "+a" in R13's OWN register regime (512thr,
//      3-deep B, accs already AGPR-homed) -> removes the 64 copies/step
//      (R13's VALUBusy 16.9% = 14.6us). R15's disaster was the same
//      constraint in a LOW-pressure regime where the allocator arch-homed
//      the accs and copied the other way; regime matters.
//  (2) B register prefetch depth 3 -> 4 (one more step of vmcnt slack vs
//      ~500cyc L2 latency).
// Everything else (STAGE_A, KA, epilogue, grids) is R13 verbatim.

#define BATCH 32
#define C_IN 256
#define OCH 256
#define HIN 58
#define WIN2 58
#define HOUT 56
#define WOUT 56
#define TAPS 9
#define WWORDS 8            // 256 channels / 32 bits
#define HWIN (HIN * WIN2)   // 3364
#define HWOUT (HOUT * WOUT) // 3136
#define NPOS (BATCH * HWIN) // 107648

#define AP 144              // LDS bytes per input position (128 ch + 16 pad:
                            // 16B-slot stride 9 (odd) -> b128 slots rotate, ~conflict-free)

typedef int   i32x4  __attribute__((ext_vector_type(4)));
typedef int   i32x16 __attribute__((ext_vector_type(16)));
typedef float f32x4  __attribute__((ext_vector_type(4)));

// MFMA inline asm (numerics verified R9-R15, absmax 0.0). "+a": AGPR-native
// accumulator — in THIS kernel's pressure regime the accs are AGPR-homed
// anyway, so this removes the v_accvgpr copies rather than adding them.
#define MFMA(acc, va, vb) \
    asm volatile("v_mfma_i32_32x32x32_i8 %0, %1, %2, %0" : "+a"(acc) : "v"(va), "v"(vb))

// ---------------------------------------------------------------------------
// Kernel 1: bit-pack x. Thread <-> one position, all 8 words (R14, verified).
// Reads 256B-coalesced per channel step; writes 32B/lane contiguous.
// ---------------------------------------------------------------------------
__global__ __launch_bounds__(256) void pack_x_kernel(
    const float* __restrict__ x, uint32_t* __restrict__ xp)
{
    int p = blockIdx.x * 256 + threadIdx.x;      // 421 blocks, tail-guarded
    if (p >= NPOS) return;
    int b = p / HWIN;
    int r = p - b * HWIN;
    const float* xb = x + (size_t)b * C_IN * HWIN + r;
    uint32_t w[8];
    #pragma unroll
    for (int k = 0; k < 8; ++k) {
        uint32_t m = 0u;
        #pragma unroll
        for (int j = 0; j < 32; ++j)
            m |= (xb[(size_t)(k * 32 + j) * HWIN] > 0.5f ? 1u : 0u) << j;
        w[k] = m;
    }
    *(uint4*)(xp + (size_t)p * WWORDS)     = make_uint4(w[0], w[1], w[2], w[3]);
    *(uint4*)(xp + (size_t)p * WWORDS + 4) = make_uint4(w[4], w[5], w[6], w[7]);
}

// ---------------------------------------------------------------------------
// Kernel 2: pack weights to i8 {+1,-1}, STEP-MAJOR (unchanged, verified):
//   wq8s[((s*2 + e)*256 + o)*16 + j], s = kh*36 + tap*4 + kb,
//   weight channel c = kh*128 + kb*32 + e*16 + j. Also alpha per o.
// ---------------------------------------------------------------------------
__global__ __launch_bounds__(256) void pack_w8_kernel(
    const float* __restrict__ wt, char* __restrict__ wq8s, float* __restrict__ sA)
{
    int o = blockIdx.x;
    int c = threadIdx.x;
    const float* wb = wt + ((size_t)o * C_IN + c) * TAPS;
    float s = 0.f;
    char sg[TAPS];
    #pragma unroll
    for (int t = 0; t < TAPS; ++t) {
        float v = wb[t];
        s += fabsf(v);
        sg[t] = (v >= 0.0f) ? (char)1 : (char)-1;
    }
    int kh = c >> 7;
    int kb = (c >> 5) & 3;
    int e  = (c >> 4) & 1;
    int j  = c & 15;
    #pragma unroll
    for (int t = 0; t < TAPS; ++t) {
        int st = kh * 36 + t * 4 + kb;
        wq8s[(size_t)((st * 2 + e) * 256 + o) * 16 + j] = sg[t];
    }

    __shared__ float red[256];
    red[c] = s;
    __syncthreads();
    for (int off = 128; off > 0; off >>= 1) {
        if (c < off) red[c] += red[c + off];
        __syncthreads();
    }
    if (c == 0) sA[o] = red[0] / (float)(C_IN * HWIN);
}

// ---------------------------------------------------------------------------
// Kernel 3: main i8-MFMA conv (R13 structure). Block = 2 output rows
// (M=128: 112 valid) x N=256 o. 8 waves (512 thr), wave = 2M x 2N quad of
// 32x32x32 tiles.
// A: bit->+-1 expand into LDS per K-half (stride AP=144), restaged once at
//    s=36 (the only mid-loop barriers). In-step ds_reads: with no barriers
//    between steps the compiler hoists/schedules them across iterations.
// B: registers straight from global (L2-resident), 4-deep prefetch.
// ---------------------------------------------------------------------------
__global__ __launch_bounds__(512)
void xnor_mfma_kernel(
    const uint32_t* __restrict__ xp, const char* __restrict__ wq8s,
    const float* __restrict__ sA, float* __restrict__ out)
{
    __shared__ __attribute__((aligned(16))) char lds[36864]; // A 33,408 / Cbuf 36,864
    char* Alds = lds;
    float* Cbuf = (float*)lds;                   // epilogue alias

    int blk = blockIdx.x;                        // 0..895
    int b   = blk / 28;                          // 28 row-pairs per image
    int rp  = blk - b * 28;
    int oy0 = rp * 2;
    int tid  = threadIdx.x;
    int wv   = tid >> 6;
    int lane = tid & 63;
    int l31  = lane & 31;
    int e    = lane >> 5;
    int mgrp = wv & 1;                           // M-half of this wave
    int ngrp = wv >> 1;                          // o-group (64 o)

    // Per-lane A-frag base for the wave's 2 M-subtiles (row = l31).
    int baseA[2];
    #pragma unroll
    for (int mi = 0; mi < 2; ++mi) {
        int p = (mgrp * 2 + mi) * 32 + l31;      // 0..127
        int r = (p * 586) >> 15;                 // p/56 exact for p<=127
        int c = p - 56 * r;
        baseA[mi] = (r * 58 + c) * AP + e * 16;
    }
    // B-fragment per-lane base in step-major wq8s; step stride = 8192 B.
    const char* pb = wq8s + ((size_t)e * 256 + (size_t)(ngrp * 64 + l31)) * 16;
    float al0 = sA[ngrp * 64 + l31];
    float al1 = sA[ngrp * 64 + 32 + l31];

    i32x16 acc00 = {0}, acc01 = {0}, acc10 = {0}, acc11 = {0};
    asm volatile("" : "+a"(acc00), "+a"(acc01), "+a"(acc10), "+a"(acc11)); // pin init above
    asm volatile("s_nop 7\n\ts_nop 7");          // accvgpr_write -> MFMA srcC guard

// A K-step LDS offset (compile-time under full unroll).
#define KA(s) ((((((s) % 36) >> 2) / 3) * 58 + ((((s) % 36) >> 2) % 3)) * AP + ((s) & 3) * 32)

// Expand bit-packed x into +-1 bytes for K-half KH (multiply-spread,
// verified R9-R15). 464 active threads x 4 rows.
#define STAGE_A(KH)                                                        \
    {                                                                      \
        _Pragma("unroll")                                                  \
        for (int ir = 0; ir < 4; ++ir) {                                   \
            if (tid < 464) {                                               \
                int iw = tid >> 3, c16 = tid & 7;                          \
                uint32_t wvx = xp[((size_t)(b * HIN + oy0 + ir) * WIN2 + iw) * WWORDS \
                                  + (KH) * 4 + (c16 >> 1)];                \
                uint32_t bits = (c16 & 1) ? (wvx >> 16) : (wvx & 0xFFFFu); \
                i32x4 v;                                                   \
                _Pragma("unroll")                                          \
                for (int d = 0; d < 4; ++d) {                              \
                    uint32_t n  = (bits >> (4 * d)) & 0xFu;                \
                    uint32_t sp = (n * 0x204081u) & 0x01010101u;           \
                    v[d] = (int)~(sp * 0xFEu);                             \
                }                                                          \
                *(i32x4*)(Alds + (ir * 58 + iw) * AP + c16 * 16) = v;      \
            }                                                              \
        }                                                                  \
    }

    STAGE_A(0);

    // B prefetch prologue: steps 0..3 in registers (4-deep).
    i32x4 rb0[4], rb1[4];
    #pragma unroll
    for (int q = 0; q < 4; ++q) {
        rb0[q] = *(const i32x4*)(pb + (size_t)q * 8192);
        rb1[q] = *(const i32x4*)(pb + (size_t)q * 8192 + 512);
    }
    __syncthreads();

    #pragma unroll
    for (int s = 0; s < 72; ++s) {               // s = kh*36 + tap*4 + kb
        if (s == 36) {                           // half-K A restage: the ONLY
            __syncthreads();                     // mid-loop barriers
            STAGE_A(1);
            __syncthreads();
        }
        const int ka = KA(s);                    // compile-time imm

        i32x4 a0 = *(const i32x4*)(Alds + baseA[0] + ka);
        i32x4 a1 = *(const i32x4*)(Alds + baseA[1] + ka);
        i32x4 b0 = rb0[s & 3];
        i32x4 b1 = rb1[s & 3];
        MFMA(acc00, a0, b0);
        MFMA(acc01, a0, b1);
        MFMA(acc10, a1, b0);
        MFMA(acc11, a1, b1);

        const int s4 = (s + 4 > 71) ? 71 : s + 4;          // tail reload harmless
        rb0[s & 3] = *(const i32x4*)(pb + (size_t)s4 * 8192);
        rb1[s & 3] = *(const i32x4*)(pb + (size_t)s4 * 8192 + 512);
    }

    asm volatile("s_nop 7\n\ts_nop 7");          // MFMA -> accvgpr_read guard

    // Epilogue (verbatim R13, verified): D layout col = l31,
    // row = (reg&3) + 8*(reg>>2) + 4*e. 4 quarter-M phases via Cbuf[o][36].
    size_t ob = ((size_t)b * OCH) * HWOUT + (size_t)oy0 * WOUT;
    #pragma unroll
    for (int q = 0; q < 4; ++q) {
        __syncthreads();
        if (mgrp == (q >> 1)) {
            const int mi = q & 1;
            #pragma unroll
            for (int ni = 0; ni < 2; ++ni) {
                float al = ni ? al1 : al0;
                int o = ngrp * 64 + ni * 32 + l31;
                i32x16 A;
                if (mi == 0 && ni == 0) A = acc00;
                else if (mi == 0)       A = acc01;
                else if (ni == 0)       A = acc10;
                else                    A = acc11;
                #pragma unroll
                for (int g = 0; g < 4; ++g) {
                    f32x4 vv;
                    vv[0] = al * (float)A[4 * g + 0];
                    vv[1] = al * (float)A[4 * g + 1];
                    vv[2] = al * (float)A[4 * g + 2];
                    vv[3] = al * (float)A[4 * g + 3];
                    int pl = g * 8 + 4 * e;                // pos within quarter
                    *(f32x4*)(Cbuf + (size_t)o * 36 + pl) = vv;
                }
            }
        }
        __syncthreads();
        #pragma unroll 1
        for (int i = 0; i < 16; ++i) {           // flush 256 o x 32 pos
            int idx = i * 512 + tid;
            int o = idx >> 5, pl = idx & 31;
            int pg = q * 32 + pl;
            if (pg < 112) {
                int r = (pg >= 56) ? 1 : 0;
                int c = pg - 56 * r;
                out[ob + (size_t)o * HWOUT + r * WOUT + c] = Cbuf[o * 36 + pl];
            }
        }
    }
#undef STAGE_A
#undef KA
}

// ---------------------------------------------------------------------------
extern "C" void kernel_launch(void* const* d_in, const int* in_sizes, int n_in,
                              void* d_out, int out_size, void* d_ws, size_t ws_size,
                              hipStream_t stream)
{
    const float* x  = (const float*)d_in[0];
    const float* wt = (const float*)d_in[1];
    float* out = (float*)d_out;

    char* ws = (char*)d_ws;
    uint32_t* xp   = (uint32_t*)ws;                         // 3,444,736 B
    char*     wq8s = (char*)(ws + 3444736);                 //   589,824 B
    float*    sAp  = (float*)(ws + 3444736 + 589824);       //     1,024 B

    // 1) pack x bits: 421 blocks (tail-guarded)
    pack_x_kernel<<<dim3((NPOS + 255) / 256), dim3(256), 0, stream>>>(x, xp);

    // 2) pack weights to +-1 i8, step-major + alpha
    pack_w8_kernel<<<dim3(OCH), dim3(256), 0, stream>>>(wt, wq8s, sAp);

    // 3) main: 32 images x 28 output-row-pairs, 512 threads (8 waves)
    xnor_mfma_kernel<<<dim3(896), dim3(512), 0, stream>>>(xp, wq8s, sAp, out);
}

// Round 14
// 259.496 us; speedup vs baseline: 1.8255x; 1.0397x over previous
//
#include <hip/hip_runtime.h>
#include <stdint.h>

// x: (32, 256, 58, 58) f32 binary {0,1};  w: (256, 256, 3, 3) f32
// out: (32, 256, 56, 56) f32 = alpha[o]*(2S - 2304)
// R17: single-token A/B vs the 86.2us champion (R13): MFMA asm volatile ->
// non-volatile. Volatile pins all 288 MFMAs in program order (volatile asm
// can't reorder past volatile asm), blocking cross-step pipelining of the
// 4 independent acc chains on the fully-unrolled K-loop. Constraints alone
// encode the true deps. Everything else byte-frozen at champion state
// (B-depth 3, "+v" accs, 512 thr, R14 pack_x which is -4us vs old).
// R16 post-mortem: "+a" burned +12 arch regs, occupancy 33->18, 91.7us —
// both directions of the register-class-constraint war lose; stop fighting.

#define BATCH 32
#define C_IN 256
#define OCH 256
#define HIN 58
#define WIN2 58
#define HOUT 56
#define WOUT 56
#define TAPS 9
#define WWORDS 8            // 256 channels / 32 bits
#define HWIN (HIN * WIN2)   // 3364
#define HWOUT (HOUT * WOUT) // 3136
#define NPOS (BATCH * HWIN) // 107648

#define AP 144              // LDS bytes per input position (128 ch + 16 pad:
                            // 16B-slot stride 9 (odd) -> b128 slots rotate, ~conflict-free)

typedef int   i32x4  __attribute__((ext_vector_type(4)));
typedef int   i32x16 __attribute__((ext_vector_type(16)));
typedef float f32x4  __attribute__((ext_vector_type(4)));

// MFMA inline asm (numerics verified R9-R16, absmax 0.0). NON-volatile:
// deps are fully encoded by "+v"/"v" constraints; the scheduler may now
// interleave independent acc chains across K-steps.
#define MFMA(acc, va, vb) \
    asm("v_mfma_i32_32x32x32_i8 %0, %1, %2, %0" : "+v"(acc) : "v"(va), "v"(vb))

// ---------------------------------------------------------------------------
// Kernel 1: bit-pack x. Thread <-> one position, all 8 words (R14, verified).
// Reads 256B-coalesced per channel step; writes 32B/lane contiguous.
// ---------------------------------------------------------------------------
__global__ __launch_bounds__(256) void pack_x_kernel(
    const float* __restrict__ x, uint32_t* __restrict__ xp)
{
    int p = blockIdx.x * 256 + threadIdx.x;      // 421 blocks, tail-guarded
    if (p >= NPOS) return;
    int b = p / HWIN;
    int r = p - b * HWIN;
    const float* xb = x + (size_t)b * C_IN * HWIN + r;
    uint32_t w[8];
    #pragma unroll
    for (int k = 0; k < 8; ++k) {
        uint32_t m = 0u;
        #pragma unroll
        for (int j = 0; j < 32; ++j)
            m |= (xb[(size_t)(k * 32 + j) * HWIN] > 0.5f ? 1u : 0u) << j;
        w[k] = m;
    }
    *(uint4*)(xp + (size_t)p * WWORDS)     = make_uint4(w[0], w[1], w[2], w[3]);
    *(uint4*)(xp + (size_t)p * WWORDS + 4) = make_uint4(w[4], w[5], w[6], w[7]);
}

// ---------------------------------------------------------------------------
// Kernel 2: pack weights to i8 {+1,-1}, STEP-MAJOR (unchanged, verified):
//   wq8s[((s*2 + e)*256 + o)*16 + j], s = kh*36 + tap*4 + kb,
//   weight channel c = kh*128 + kb*32 + e*16 + j. Also alpha per o.
// ---------------------------------------------------------------------------
__global__ __launch_bounds__(256) void pack_w8_kernel(
    const float* __restrict__ wt, char* __restrict__ wq8s, float* __restrict__ sA)
{
    int o = blockIdx.x;
    int c = threadIdx.x;
    const float* wb = wt + ((size_t)o * C_IN + c) * TAPS;
    float s = 0.f;
    char sg[TAPS];
    #pragma unroll
    for (int t = 0; t < TAPS; ++t) {
        float v = wb[t];
        s += fabsf(v);
        sg[t] = (v >= 0.0f) ? (char)1 : (char)-1;
    }
    int kh = c >> 7;
    int kb = (c >> 5) & 3;
    int e  = (c >> 4) & 1;
    int j  = c & 15;
    #pragma unroll
    for (int t = 0; t < TAPS; ++t) {
        int st = kh * 36 + t * 4 + kb;
        wq8s[(size_t)((st * 2 + e) * 256 + o) * 16 + j] = sg[t];
    }

    __shared__ float red[256];
    red[c] = s;
    __syncthreads();
    for (int off = 128; off > 0; off >>= 1) {
        if (c < off) red[c] += red[c + off];
        __syncthreads();
    }
    if (c == 0) sA[o] = red[0] / (float)(C_IN * HWIN);
}

// ---------------------------------------------------------------------------
// Kernel 3: main i8-MFMA conv (champion structure, R13). Block = 2 output
// rows (M=128: 112 valid) x N=256 o. 8 waves (512 thr), wave = 2M x 2N quad
// of 32x32x32 tiles.
// A: bit->+-1 expand into LDS per K-half (stride AP=144), restaged once at
//    s=36 (the only mid-loop barriers).
// B: registers straight from global (L2-resident), 3-deep prefetch.
// ---------------------------------------------------------------------------
__global__ __launch_bounds__(512)
void xnor_mfma_kernel(
    const uint32_t* __restrict__ xp, const char* __restrict__ wq8s,
    const float* __restrict__ sA, float* __restrict__ out)
{
    __shared__ __attribute__((aligned(16))) char lds[36864]; // A 33,408 / Cbuf 36,864
    char* Alds = lds;
    float* Cbuf = (float*)lds;                   // epilogue alias

    int blk = blockIdx.x;                        // 0..895
    int b   = blk / 28;                          // 28 row-pairs per image
    int rp  = blk - b * 28;
    int oy0 = rp * 2;
    int tid  = threadIdx.x;
    int wv   = tid >> 6;
    int lane = tid & 63;
    int l31  = lane & 31;
    int e    = lane >> 5;
    int mgrp = wv & 1;                           // M-half of this wave
    int ngrp = wv >> 1;                          // o-group (64 o)

    // Per-lane A-frag base for the wave's 2 M-subtiles (row = l31).
    int baseA[2];
    #pragma unroll
    for (int mi = 0; mi < 2; ++mi) {
        int p = (mgrp * 2 + mi) * 32 + l31;      // 0..127
        int r = (p * 586) >> 15;                 // p/56 exact for p<=127
        int c = p - 56 * r;
        baseA[mi] = (r * 58 + c) * AP + e * 16;
    }
    // B-fragment per-lane base in step-major wq8s; step stride = 8192 B.
    const char* pb = wq8s + ((size_t)e * 256 + (size_t)(ngrp * 64 + l31)) * 16;
    float al0 = sA[ngrp * 64 + l31];
    float al1 = sA[ngrp * 64 + 32 + l31];

    i32x16 acc00 = {0}, acc01 = {0}, acc10 = {0}, acc11 = {0};
    asm volatile("" : "+v"(acc00), "+v"(acc01), "+v"(acc10), "+v"(acc11)); // pin init above
    asm volatile("s_nop 7\n\ts_nop 7");          // VALU->MFMA srcC hazard guard

// A K-step LDS offset (compile-time under full unroll).
#define KA(s) ((((((s) % 36) >> 2) / 3) * 58 + ((((s) % 36) >> 2) % 3)) * AP + ((s) & 3) * 32)

// Expand bit-packed x into +-1 bytes for K-half KH (multiply-spread,
// verified R9-R16). 464 active threads x 4 rows.
#define STAGE_A(KH)                                                        \
    {                                                                      \
        _Pragma("unroll")                                                  \
        for (int ir = 0; ir < 4; ++ir) {                                   \
            if (tid < 464) {                                               \
                int iw = tid >> 3, c16 = tid & 7;                          \
                uint32_t wvx = xp[((size_t)(b * HIN + oy0 + ir) * WIN2 + iw) * WWORDS \
                                  + (KH) * 4 + (c16 >> 1)];                \
                uint32_t bits = (c16 & 1) ? (wvx >> 16) : (wvx & 0xFFFFu); \
                i32x4 v;                                                   \
                _Pragma("unroll")                                          \
                for (int d = 0; d < 4; ++d) {                              \
                    uint32_t n  = (bits >> (4 * d)) & 0xFu;                \
                    uint32_t sp = (n * 0x204081u) & 0x01010101u;           \
                    v[d] = (int)~(sp * 0xFEu);                             \
                }                                                          \
                *(i32x4*)(Alds + (ir * 58 + iw) * AP + c16 * 16) = v;      \
            }                                                              \
        }                                                                  \
    }

    STAGE_A(0);

    // B prefetch prologue: steps 0,1,2 in registers (3-deep, champion).
    i32x4 rb0[3], rb1[3];
    #pragma unroll
    for (int q = 0; q < 3; ++q) {
        rb0[q] = *(const i32x4*)(pb + (size_t)q * 8192);
        rb1[q] = *(const i32x4*)(pb + (size_t)q * 8192 + 512);
    }
    __syncthreads();

    #pragma unroll
    for (int s = 0; s < 72; ++s) {               // s = kh*36 + tap*4 + kb
        if (s == 36) {                           // half-K A restage: the ONLY
            __syncthreads();                     // mid-loop barriers
            STAGE_A(1);
            __syncthreads();
        }
        const int ka = KA(s);                    // compile-time imm

        i32x4 a0 = *(const i32x4*)(Alds + baseA[0] + ka);
        i32x4 a1 = *(const i32x4*)(Alds + baseA[1] + ka);
        i32x4 b0 = rb0[s % 3];
        i32x4 b1 = rb1[s % 3];
        MFMA(acc00, a0, b0);
        MFMA(acc01, a0, b1);
        MFMA(acc10, a1, b0);
        MFMA(acc11, a1, b1);

        const int s3 = (s + 3 > 71) ? 71 : s + 3;          // tail reload harmless
        rb0[s % 3] = *(const i32x4*)(pb + (size_t)s3 * 8192);
        rb1[s % 3] = *(const i32x4*)(pb + (size_t)s3 * 8192 + 512);
    }

    asm volatile("s_nop 7\n\ts_nop 7");          // MFMA -> epilogue read guard

    // Epilogue (verbatim champion, verified): D layout col = l31,
    // row = (reg&3) + 8*(reg>>2) + 4*e. 4 quarter-M phases via Cbuf[o][36].
    size_t ob = ((size_t)b * OCH) * HWOUT + (size_t)oy0 * WOUT;
    #pragma unroll
    for (int q = 0; q < 4; ++q) {
        __syncthreads();
        if (mgrp == (q >> 1)) {
            const int mi = q & 1;
            #pragma unroll
            for (int ni = 0; ni < 2; ++ni) {
                float al = ni ? al1 : al0;
                int o = ngrp * 64 + ni * 32 + l31;
                i32x16 A;
                if (mi == 0 && ni == 0) A = acc00;
                else if (mi == 0)       A = acc01;
                else if (ni == 0)       A = acc10;
                else                    A = acc11;
                #pragma unroll
                for (int g = 0; g < 4; ++g) {
                    f32x4 vv;
                    vv[0] = al * (float)A[4 * g + 0];
                    vv[1] = al * (float)A[4 * g + 1];
                    vv[2] = al * (float)A[4 * g + 2];
                    vv[3] = al * (float)A[4 * g + 3];
                    int pl = g * 8 + 4 * e;                // pos within quarter
                    *(f32x4*)(Cbuf + (size_t)o * 36 + pl) = vv;
                }
            }
        }
        __syncthreads();
        #pragma unroll 1
        for (int i = 0; i < 16; ++i) {           // flush 256 o x 32 pos
            int idx = i * 512 + tid;
            int o = idx >> 5, pl = idx & 31;
            int pg = q * 32 + pl;
            if (pg < 112) {
                int r = (pg >= 56) ? 1 : 0;
                int c = pg - 56 * r;
                out[ob + (size_t)o * HWOUT + r * WOUT + c] = Cbuf[o * 36 + pl];
            }
        }
    }
#undef STAGE_A
#undef KA
}

// ---------------------------------------------------------------------------
extern "C" void kernel_launch(void* const* d_in, const int* in_sizes, int n_in,
                              void* d_out, int out_size, void* d_ws, size_t ws_size,
                              hipStream_t stream)
{
    const float* x  = (const float*)d_in[0];
    const float* wt = (const float*)d_in[1];
    float* out = (float*)d_out;

    char* ws = (char*)d_ws;
    uint32_t* xp   = (uint32_t*)ws;                         // 3,444,736 B
    char*     wq8s = (char*)(ws + 3444736);                 //   589,824 B
    float*    sAp  = (float*)(ws + 3444736 + 589824);       //     1,024 B

    // 1) pack x bits: 421 blocks (tail-guarded)
    pack_x_kernel<<<dim3((NPOS + 255) / 256), dim3(256), 0, stream>>>(x, xp);

    // 2) pack weights to +-1 i8, step-major + alpha
    pack_w8_kernel<<<dim3(OCH), dim3(256), 0, stream>>>(wt, wq8s, sAp);

    // 3) main: 32 images x 28 output-row-pairs, 512 threads (8 waves)
    xnor_mfma_kernel<<<dim3(896), dim3(512), 0, stream>>>(xp, wq8s, sAp, out);
}